// Round 3
// baseline (11307.207 us; speedup 1.0000x reference)
//
#include <hip/hip_runtime.h>
#include <hip/hip_bf16.h>

typedef float f32x4 __attribute__((ext_vector_type(4)));
typedef __bf16 bf16x8 __attribute__((ext_vector_type(8)));

__device__ __forceinline__ unsigned short f2b(float f) {
  unsigned u = __builtin_bit_cast(unsigned, f);
  unsigned r = (u + 0x7fffu + ((u >> 16) & 1u)) >> 16;   // RNE
  return (unsigned short)r;
}

__device__ __forceinline__ bf16x8 pack8(float4 a, float4 b) {
  union { __hip_bfloat162 h2[4]; bf16x8 v; } u;
  u.h2[0] = __float22bfloat162_rn(make_float2(a.x, a.y));
  u.h2[1] = __float22bfloat162_rn(make_float2(a.z, a.w));
  u.h2[2] = __float22bfloat162_rn(make_float2(b.x, b.y));
  u.h2[3] = __float22bfloat162_rn(make_float2(b.z, b.w));
  return u.v;
}

// ---------------- transpose fp32 [R][C] -> bf16 [C][R] ----------------
__global__ __launch_bounds__(256) void tconv(const float* __restrict__ in,
                                             unsigned short* __restrict__ out,
                                             int R, int C) {
  __shared__ unsigned short tile[32][33];
  const int tx = threadIdx.x & 31, ty = threadIdx.x >> 5;
  const int c0 = blockIdx.x * 32, r0 = blockIdx.y * 32;
#pragma unroll
  for (int p = 0; p < 4; ++p) {
    int r = ty + p * 8;
    tile[r][tx] = f2b(in[(size_t)(r0 + r) * C + c0 + tx]);
  }
  __syncthreads();
#pragma unroll
  for (int p = 0; p < 4; ++p) {
    int cc = ty + p * 8;
    out[(size_t)(c0 + cc) * R + r0 + tx] = tile[tx][cc];
  }
}

// ---------------- combined bias: [4][1024] = bz, br, bhi, bhr ----------
__global__ __launch_bounds__(256) void bprep(const float* __restrict__ bias,
                                             float* __restrict__ bc) {
  const int u = blockIdx.x * 256 + threadIdx.x;  // 0..1023
  bc[u]        = bias[u]        + bias[3072 + u];
  bc[1024 + u] = bias[1024 + u] + bias[4096 + u];
  bc[2048 + u] = bias[2048 + u];
  bc[3072 + u] = bias[5120 + u];
}

// ---------------- zero init: hbf0 + barrier counter --------------------
__global__ __launch_bounds__(256) void zinit(uint4* __restrict__ hbf0,
                                             unsigned int* __restrict__ bar) {
  const int id = blockIdx.x * 256 + threadIdx.x;   // 32768 uint4 = 512 KB
  hbf0[id] = make_uint4(0u, 0u, 0u, 0u);
  if (id == 0) *bar = 0u;
}

// ---------------- persistent GRU scan ----------------------------------
// 256 blocks (1/CU) x 256 thr. Block owns rows r0..r0+63, u-cols cg*16..+15.
// Waves split K_eff = 512(x@W) + 1024(h@U) four ways; W/U fragments held in
// VGPRs for all 256 timesteps (144 VGPRs/lane). fp32 h state lives in LDS
// (block-private); bf16 h broadcast via global double buffer + barrier.
__global__ __launch_bounds__(256, 1) void gru_persist(
    const float* __restrict__ x,             // fp32 [256][256][512]
    const unsigned short* __restrict__ Wt,   // bf16 [3072][512]
    const unsigned short* __restrict__ Ut,   // bf16 [3072][1024]
    const float* __restrict__ biasC,         // [4][1024]
    unsigned short* __restrict__ hA,         // bf16 [256][1024] (read at even t)
    unsigned short* __restrict__ hB,
    float* __restrict__ out,                 // fp32 [256][1024]
    unsigned int* __restrict__ bar)
{
  __shared__ float part[16 * 16 * 68];   // [(w*4+c)*16+col][row pitch 68]
  __shared__ float h32[16 * 68];         // [col][row pitch 68] fp32 state

  const int tid = threadIdx.x;
  const int lane = tid & 63;
  const int w = tid >> 6;
  const int cg = (int)blockIdx.x >> 2;          // 0..63
  const int r0 = ((int)blockIdx.x & 3) << 6;    // 0,64,128,192
  const int u16l = lane & 15, kq = lane >> 4;

  for (int i = tid; i < 16 * 68; i += 256) h32[i] = 0.f;

  // ---- load W/U fragments into registers (held for all 256 steps) ----
  bf16x8 bw[12][3];
#pragma unroll
  for (int g = 0; g < 3; ++g) {
    const unsigned short* wp = Wt + ((size_t)(g * 1024 + cg * 16 + u16l)) * 512 + w * 128 + kq * 8;
#pragma unroll
    for (int ks = 0; ks < 4; ++ks) bw[ks][g] = *(const bf16x8*)(wp + ks * 32);
    const unsigned short* up = Ut + ((size_t)(g * 1024 + cg * 16 + u16l)) * 1024 + w * 256 + kq * 8;
#pragma unroll
    for (int ks = 0; ks < 8; ++ks) bw[4 + ks][g] = *(const bf16x8*)(up + ks * 32);
  }

  // epilogue mapping: thread -> (col = tid&15, rows erow0..+3)
  const int ecol = tid & 15;
  const int erow0 = (tid >> 4) << 2;
  const int cu = cg * 16 + ecol;
  const float bz = biasC[cu], br = biasC[1024 + cu];
  const float bhi = biasC[2048 + cu], bhr = biasC[3072 + cu];

  const float* xb0 = x + (size_t)(r0 + u16l) * 131072 + w * 128 + kq * 8;
  unsigned int tgt = 0;

  for (int t = 0; t < 256; ++t) {
    const unsigned short* hin = (t & 1) ? hB : hA;
    unsigned short* hout = (t & 1) ? hA : hB;

    f32x4 az[4], ar_[4], axh[4], arh[4];
#pragma unroll
    for (int rg = 0; rg < 4; ++rg) { az[rg] = 0.f; ar_[rg] = 0.f; axh[rg] = 0.f; arh[rg] = 0.f; }

    const float* xt = xb0 + t * 512;
    float4 fa[2][4], fb[2][4];
    uint4 hfr[2][8];
    // prologue: loads for rowgroup 0
    {
      const unsigned short* hp = hin + (size_t)(r0 + u16l) * 1024 + w * 256 + kq * 8;
#pragma unroll
      for (int ks = 0; ks < 4; ++ks) {
        fa[0][ks] = *(const float4*)(xt + ks * 32);
        fb[0][ks] = *(const float4*)(xt + ks * 32 + 4);
      }
#pragma unroll
      for (int ks = 0; ks < 8; ++ks) hfr[0][ks] = *(const uint4*)(hp + ks * 32);
    }

#pragma unroll
    for (int rg = 0; rg < 4; ++rg) {
      const int cb = rg & 1, nb = cb ^ 1;
      if (rg < 3) {   // prefetch rowgroup rg+1 while computing rg
        const float* xp = xt + (size_t)(rg + 1) * 2097152;   // 16 rows * 131072
        const unsigned short* hp = hin + (size_t)(r0 + (rg + 1) * 16 + u16l) * 1024 + w * 256 + kq * 8;
#pragma unroll
        for (int ks = 0; ks < 4; ++ks) {
          fa[nb][ks] = *(const float4*)(xp + ks * 32);
          fb[nb][ks] = *(const float4*)(xp + ks * 32 + 4);
        }
#pragma unroll
        for (int ks = 0; ks < 8; ++ks) hfr[nb][ks] = *(const uint4*)(hp + ks * 32);
      }
      // x-part: K 0..511 quarter (4 ksteps)
#pragma unroll
      for (int ks = 0; ks < 4; ++ks) {
        bf16x8 af = pack8(fa[cb][ks], fb[cb][ks]);
        az[rg]  = __builtin_amdgcn_mfma_f32_16x16x32_bf16(af, bw[ks][0], az[rg], 0, 0, 0);
        ar_[rg] = __builtin_amdgcn_mfma_f32_16x16x32_bf16(af, bw[ks][1], ar_[rg], 0, 0, 0);
        axh[rg] = __builtin_amdgcn_mfma_f32_16x16x32_bf16(af, bw[ks][2], axh[rg], 0, 0, 0);
      }
      // h-part: K 512..1535 quarter (8 ksteps)
#pragma unroll
      for (int ks = 0; ks < 8; ++ks) {
        bf16x8 af = __builtin_bit_cast(bf16x8, hfr[cb][ks]);
        az[rg]  = __builtin_amdgcn_mfma_f32_16x16x32_bf16(af, bw[4 + ks][0], az[rg], 0, 0, 0);
        ar_[rg] = __builtin_amdgcn_mfma_f32_16x16x32_bf16(af, bw[4 + ks][1], ar_[rg], 0, 0, 0);
        arh[rg] = __builtin_amdgcn_mfma_f32_16x16x32_bf16(af, bw[4 + ks][2], arh[rg], 0, 0, 0);
      }
    }

    // ---- K-split partials -> LDS (b128, conflict-free) ----
#pragma unroll
    for (int rg = 0; rg < 4; ++rg) {
      const int rowo = rg * 16 + kq * 4;
      *(f32x4*)&part[((w * 4 + 0) * 16 + u16l) * 68 + rowo] = az[rg];
      *(f32x4*)&part[((w * 4 + 1) * 16 + u16l) * 68 + rowo] = ar_[rg];
      *(f32x4*)&part[((w * 4 + 2) * 16 + u16l) * 68 + rowo] = axh[rg];
      *(f32x4*)&part[((w * 4 + 3) * 16 + u16l) * 68 + rowo] = arh[rg];
    }
    __syncthreads();

    // ---- reduce + gates ----
    f32x4 sz = 0.f, sr = 0.f, sxh = 0.f, srh = 0.f;
#pragma unroll
    for (int ww = 0; ww < 4; ++ww) {
      sz  += *(const f32x4*)&part[((ww * 4 + 0) * 16 + ecol) * 68 + erow0];
      sr  += *(const f32x4*)&part[((ww * 4 + 1) * 16 + ecol) * 68 + erow0];
      sxh += *(const f32x4*)&part[((ww * 4 + 2) * 16 + ecol) * 68 + erow0];
      srh += *(const f32x4*)&part[((ww * 4 + 3) * 16 + ecol) * 68 + erow0];
    }
    f32x4 hold = *(const f32x4*)&h32[ecol * 68 + erow0];
    f32x4 hnew;
#pragma unroll
    for (int v = 0; v < 4; ++v) {
      const float z  = 1.f / (1.f + __expf(-(sz[v] + bz)));
      const float rr = 1.f / (1.f + __expf(-(sr[v] + br)));
      const float hp = sxh[v] + bhi + rr * (srh[v] + bhr);
      const float e2 = __expf(2.f * hp);
      const float hh = 1.f - 2.f / (e2 + 1.f);
      hnew[v] = hh + z * (hold[v] - hh);
    }
    *(f32x4*)&h32[ecol * 68 + erow0] = hnew;

    if (t < 255) {
#pragma unroll
      for (int v = 0; v < 4; ++v)
        hout[(size_t)(r0 + erow0 + v) * 1024 + cu] = f2b(hnew[v]);
      // ---- device-wide barrier (monotonic counter) ----
      __syncthreads();        // all block threads' writes issued
      __threadfence();        // make them device-visible
      if (tid == 0) {
        __hip_atomic_fetch_add(bar, 1u, __ATOMIC_RELEASE, __HIP_MEMORY_SCOPE_AGENT);
        tgt += 256;
        while (__hip_atomic_load(bar, __ATOMIC_ACQUIRE, __HIP_MEMORY_SCOPE_AGENT) < tgt)
          __builtin_amdgcn_s_sleep(2);
      }
      __syncthreads();        // block waits on tid0's acquire
    } else {
#pragma unroll
      for (int v = 0; v < 4; ++v)
        out[(size_t)(r0 + erow0 + v) * 1024 + cu] = hnew[v];
    }
  }
}

extern "C" void kernel_launch(void* const* d_in, const int* in_sizes, int n_in,
                              void* d_out, int out_size, void* d_ws, size_t ws_size,
                              hipStream_t stream) {
  (void)in_sizes; (void)n_in; (void)out_size; (void)ws_size;
  const float* x    = (const float*)d_in[0];   // (256,256,512)
  const float* Wk   = (const float*)d_in[1];   // (512,3072)
  const float* Rk   = (const float*)d_in[2];   // (1024,3072)
  const float* bias = (const float*)d_in[3];   // (2,3072)
  float* out = (float*)d_out;

  char* ws = (char*)d_ws;
  unsigned short* Wt    = (unsigned short*)(ws + 0);          // 3,145,728 B
  unsigned short* Ut    = (unsigned short*)(ws + 3145728);    // 6,291,456 B
  float*          biasC = (float*)(ws + 9437184);             // 16,384 B
  unsigned short* hbf0  = (unsigned short*)(ws + 9453568);    // 524,288 B
  unsigned short* hbf1  = (unsigned short*)(ws + 9977856);    // 524,288 B
  unsigned int*   bar   = (unsigned int*)(ws + 10502144);     // 4 B (own line)

  tconv<<<dim3(96, 16), 256, 0, stream>>>(Wk, Wt, 512, 3072);
  tconv<<<dim3(96, 32), 256, 0, stream>>>(Rk, Ut, 1024, 3072);
  bprep<<<4, 256, 0, stream>>>(bias, biasC);
  zinit<<<128, 256, 0, stream>>>((uint4*)hbf0, bar);

  gru_persist<<<256, 256, 0, stream>>>(x, Wt, Ut, biasC, hbf0, hbf1, out, bar);
}